// Round 17
// baseline (96.544 us; speedup 1.0000x reference)
//
#include <hip/hip_runtime.h>
#include <math.h>

#define N_ROWS 32768
#define KCODES 1024
#define DIM 64
#define OUT_Q 1
#define OUT_PERP 2097153
#define OUT_ENC 2097154
#define GAP_QUANTA 64u   // 64 * 2^-21 ~ 3.05e-5 >> bf16-split dot err (~1e-6)

using short8 = __attribute__((ext_vector_type(8))) short;   // 8 bf16 (4 VGPR)
using f32x4  = __attribute__((ext_vector_type(4))) float;
typedef float f32x2 __attribute__((ext_vector_type(2)));

__device__ __forceinline__ unsigned umin_(unsigned a, unsigned b){return a<b?a:b;}
__device__ __forceinline__ unsigned umax_(unsigned a, unsigned b){return a>b?a:b;}
// RTNE float->bf16
__device__ __forceinline__ unsigned short f2bf(float f){
    unsigned u = __float_as_uint(f);
    unsigned r = (u + 0x7FFFu + ((u >> 16) & 1u)) >> 16;
    return (unsigned short)r;
}
__device__ __forceinline__ float bf2f(unsigned short h){
    return __uint_as_float(((unsigned)h) << 16);
}

// ---------------------------------------------------------------------------
// P: prep (64 blocks; one thread per (code, float4-chunk)).
// sqnB21[k] = (0.25 + 0.5||e_k||^2)*2^21 (fp64, 16-lane shfl reduce);
// codebook bf16-split packed in MFMA-fragment order (epack, in d_ws).
// Zeroes counts/flagcount/donecnt/lossadj.
// ---------------------------------------------------------------------------
__global__ __launch_bounds__(256) void vq_prep_kernel(
    const float* __restrict__ emb, float* __restrict__ sqnB21,
    unsigned short* __restrict__ epack, int* __restrict__ counts,
    int* __restrict__ flagcount, double* __restrict__ lossadj) {
    int t = blockIdx.x * 256 + threadIdx.x;  // 16384 threads
    int k = t >> 4, q = t & 15;
    if (t < KCODES) counts[t] = 0;
    if (t == 0) { flagcount[0] = 0; flagcount[1] = 0; lossadj[0] = 0.0; }
    int tile = k >> 4, col = k & 15;
    float4 v = ((const float4*)emb)[t];      // = emb[k*64 + q*4 ..]
    unsigned short h0=f2bf(v.x), h1=f2bf(v.y), h2=f2bf(v.z), h3=f2bf(v.w);
    unsigned short l0=f2bf(v.x-bf2f(h0)), l1=f2bf(v.y-bf2f(h1)),
                   l2=f2bf(v.z-bf2f(h2)), l3=f2bf(v.w-bf2f(h3));
    unsigned* up = (unsigned*)epack;
    unsigned idx = tile * 1024u + (q >> 1) * 64u + col * 4u + (q & 1) * 2u;
    up[idx]       = (unsigned)h0 | ((unsigned)h1 << 16);
    up[idx + 1]   = (unsigned)h2 | ((unsigned)h3 << 16);
    up[idx + 512] = (unsigned)l0 | ((unsigned)l1 << 16);
    up[idx + 513] = (unsigned)l2 | ((unsigned)l3 << 16);
    double s = (double)v.x*v.x + (double)v.y*v.y +
               (double)v.z*v.z + (double)v.w*v.w;
    s += __shfl_xor(s, 1);
    s += __shfl_xor(s, 2);
    s += __shfl_xor(s, 4);
    s += __shfl_xor(s, 8);
    if (q == 0) sqnB21[k] = (float)((0.25 + 0.5 * s) * 2097152.0);
}

// ---------------------------------------------------------------------------
// M: MEGA kernel v3 — 1024 blocks x 32 rows, in-block K-split (4 blocks/CU).
// Wave w = (rowgroup w&1, khalf w>>1): scans 512 codes for its 16 rows.
// Interleaved enc zero-stream (1 f32x4/lane/tile-iter). q+loss now computed
// FROM THE A-FRAGMENTS (x_rec = h+l, rel err ~8e-6 << 2% loss threshold) —
// no x re-read. Near-ties corrected by vq_patchfin_kernel.
// ---------------------------------------------------------------------------
__global__ __launch_bounds__(256, 4) void vq_mega_kernel(
    const float* __restrict__ x, const float* __restrict__ emb,
    const unsigned short* __restrict__ epack,
    const float* __restrict__ sqnB21, float* __restrict__ out,
    int* __restrict__ idxp, int* __restrict__ flaglist,
    int* __restrict__ flagcount, int* __restrict__ counts,
    double* __restrict__ lossp) {
    __shared__ short8 elds[8 * 256];             // 32 KB: 4+4 tiles
    __shared__ unsigned sbb[4][16], sss[4][16];
    __shared__ int sidx[32];
    __shared__ double redl[2];
    int tid = threadIdx.x;
    int bi = blockIdx.x;          // 1024 blocks x 32 rows
    int lane = tid & 63;
    int w = tid >> 6;
    int rg = w & 1;               // row-group (16 rows)
    int kh = w >> 1;              // K-half (512 codes)
    int col = lane & 15;
    int g = lane >> 4;
    int n = bi * 32 + rg * 16 + col;
    int xbase = (n >> 12) * 262144 + (n & 4095);

    // wave's enc zero region: 8 rows = 8192 floats (region base ≡8 mod 16)
    float* enc = out + OUT_ENC;
    float* zreg = enc + (size_t)(bi * 32 + w * 8) * 1024;
    f32x4* zvec = (f32x4*)(zreg + 2);
    const f32x4 zz4 = {0.f, 0.f, 0.f, 0.f};
    const f32x2 zz2 = {0.f, 0.f};

    short8 ah0, al0, ah1, al1;
#pragma unroll
    for (int j = 0; j < 8; ++j) {
        float v0 = x[xbase + (g * 8 + j) * 4096];
        unsigned short h0 = f2bf(v0);
        ah0[j] = (short)h0; al0[j] = (short)f2bf(v0 - bf2f(h0));
        float v1 = x[xbase + (32 + g * 8 + j) * 4096];
        unsigned short h1 = f2bf(v1);
        ah1[j] = (short)h1; al1[j] = (short)f2bf(v1 - bf2f(h1));
    }

    unsigned best[4] = {~0u, ~0u, ~0u, ~0u}, sec[4] = {~0u, ~0u, ~0u, ~0u};
    for (int ph = 0; ph < 8; ++ph) {
        // stage 8 tiles: slots 0..3 = khalf0 tiles ph*4+i, 4..7 = khalf1
        f32x4* dst = (f32x4*)elds;
#pragma unroll
        for (int i = 0; i < 8; ++i) {
            int tile_g = (i < 4) ? (ph * 4 + i) : (32 + ph * 4 + (i - 4));
            dst[i * 256 + tid] =
                ((const f32x4*)epack)[(size_t)tile_g * 256 + tid];
        }
        __syncthreads();
#pragma unroll
        for (int tt = 0; tt < 4; ++tt) {
            // interleaved enc zero-store (drains under MFMA)
            int zslot = (ph * 4 + tt) * 64 + lane;
            if (zslot < 2047) zvec[zslot] = zz4;
            else {
                *(f32x2*)zreg = zz2;
                *(f32x2*)(zreg + 8190) = zz2;
            }

            int code = (kh * 32 + ph * 4 + tt) * 16 + col;
            const short8* bp = elds + (kh * 4 + tt) * 256;
            short8 bh0 = bp[lane];        // h, d 0..31
            short8 bh1 = bp[64 + lane];   // h, d 32..63
            short8 bl0 = bp[128 + lane];  // l, d 0..31
            short8 bl1 = bp[192 + lane];  // l, d 32..63
            float sqv = sqnB21[code];
            f32x4 a0 = {0.f, 0.f, 0.f, 0.f}, a1 = {0.f, 0.f, 0.f, 0.f};
            a0 = __builtin_amdgcn_mfma_f32_16x16x32_bf16(ah0, bh0, a0, 0, 0, 0);
            a0 = __builtin_amdgcn_mfma_f32_16x16x32_bf16(ah1, bh1, a0, 0, 0, 0);
            a1 = __builtin_amdgcn_mfma_f32_16x16x32_bf16(ah0, bl0, a1, 0, 0, 0);
            a1 = __builtin_amdgcn_mfma_f32_16x16x32_bf16(al0, bh0, a1, 0, 0, 0);
            a1 = __builtin_amdgcn_mfma_f32_16x16x32_bf16(ah1, bl1, a1, 0, 0, 0);
            a1 = __builtin_amdgcn_mfma_f32_16x16x32_bf16(al1, bh1, a1, 0, 0, 0);
#pragma unroll
            for (int r = 0; r < 4; ++r) {
                float s = a0[r] + a1[r];
                unsigned u = (unsigned)fmaf(s, -2097152.0f, sqv);
                unsigned pk = (u << 10) | (unsigned)code;
                unsigned t = umax_(pk, best[r]);
                sec[r] = umin_(sec[r], t);
                best[r] = umin_(best[r], pk);
            }
        }
        __syncthreads();   // protect LDS; drains this phase's stores
    }
    // xor-reduce over the 16 code-columns within each 16-lane group
#pragma unroll
    for (int st = 1; st < 16; st <<= 1) {
#pragma unroll
        for (int r = 0; r < 4; ++r) {
            unsigned ob = __shfl_xor(best[r], st);
            unsigned os = __shfl_xor(sec[r], st);
            sec[r] = umin_(umin_(sec[r], os), umax_(best[r], ob));
            best[r] = umin_(best[r], ob);
        }
    }
    if (col == 0) {
#pragma unroll
        for (int r = 0; r < 4; ++r) {
            sbb[w][g * 4 + r] = best[r];
            sss[w][g * 4 + r] = sec[r];
        }
    }
    __syncthreads();
    // K-merge across wave pairs (rg, rg+2); idx/counts/flag for 32 rows
    if (tid < 32) {
        int rg2 = tid >> 4, r16 = tid & 15;
        unsigned b0 = sbb[rg2][r16], s0 = sss[rg2][r16];
        unsigned b1 = sbb[rg2 + 2][r16], s1 = sss[rg2 + 2][r16];
        unsigned s = umin_(umin_(s0, s1), umax_(b0, b1));
        unsigned b = umin_(b0, b1);
        int n2 = bi * 32 + tid;
        int ix = (int)(b & 1023u);
        sidx[tid] = ix;
        idxp[n2] = ix;
        atomicAdd(&counts[ix], 1);
        if (((s >> 10) - (b >> 10)) < GAP_QUANTA) {
            int pos = atomicAdd(flagcount, 1);
            flaglist[pos] = n2;
        }
    }
    __syncthreads();   // vmcnt(0) drain: zeros complete before the ones

    // ---- ones scatter ----
    if (tid < 32) {
        int n2 = bi * 32 + tid;
        enc[(size_t)n2 * 1024 + sidx[tid]] = 1.0f;
    }

    // ---- q + loss FROM FRAGMENTS (kh==0 waves; x_rec = h+l) ----
    if (kh == 0) {
        int iv = sidx[rg * 16 + col];
        const float4* e4a = (const float4*)(emb + iv * DIM + g * 8);
        const float4* e4b = (const float4*)(emb + iv * DIM + 32 + g * 8);
        float* qp = out + OUT_Q + xbase;
        float lsum = 0.f;
#pragma unroll
        for (int q = 0; q < 2; ++q) {
            float4 ea = e4a[q], eb = e4b[q];
#pragma unroll
            for (int jc = 0; jc < 4; ++jc) {
                int j = q * 4 + jc;
                float xa = bf2f((unsigned short)ah0[j]) +
                           bf2f((unsigned short)al0[j]);
                float xb = bf2f((unsigned short)ah1[j]) +
                           bf2f((unsigned short)al1[j]);
                float ea_ = (&ea.x)[jc], eb_ = (&eb.x)[jc];
                float da = ea_ - xa, db = eb_ - xb;
                lsum += da * da + db * db;
                qp[(g * 8 + j) * 4096] = ea_;
                qp[(32 + g * 8 + j) * 4096] = eb_;
            }
        }
        double ls = (double)lsum;
        for (int off = 32; off > 0; off >>= 1) ls += __shfl_down(ls, off);
        if (lane == 0) redl[w] = ls;
    }
    __syncthreads();
    if (tid == 0) lossp[bi] = redl[0] + redl[1];
}

// ---------------------------------------------------------------------------
// B+D: patch + finalize fused. Patch: exact fp64 re-scan of flagged rows
// (one wave per row); fixes enc/q/counts/lossadj. Then a device-scope
// done-counter elects the LAST block to run the finalize reduction.
// ---------------------------------------------------------------------------
__global__ __launch_bounds__(256) void vq_patchfin_kernel(
    const float* __restrict__ x, const float* __restrict__ emb,
    const int* __restrict__ flaglist, int* __restrict__ flagcount,
    const int* __restrict__ idxp, float* __restrict__ out,
    int* __restrict__ counts, double* __restrict__ lossadj,
    const double* __restrict__ lossp) {
    int tid = threadIdx.x;
    int lane = tid & 63;
    int gw = (blockIdx.x * 256 + tid) >> 6;  // 0..1023
    int nf = flagcount[0];
    int dg = lane & 3, kg = lane >> 2;
    for (int i = gw; i < nf; i += 1024) {
        int n = flaglist[i];
        int xoff = (n >> 12) * 262144 + (n & 4095);
        const float* xp = x + xoff + dg * 16 * 4096;
        double xd[16];
#pragma unroll
        for (int j = 0; j < 16; ++j) xd[j] = (double)xp[j * 4096];
        double best = 1e300;
        int bi = 0;
        for (int j = 0; j < 64; ++j) {
            int k = kg * 64 + j;
            const float4* e4 = (const float4*)(emb + k * DIM + dg * 16);
            double u = 0.0;
#pragma unroll
            for (int q = 0; q < 4; ++q) {
                float4 ev = e4[q];
                double e0 = ev.x, e1 = ev.y, e2 = ev.z, e3 = ev.w;
                u += e0 * (0.5 * e0 - xd[q * 4 + 0]);
                u += e1 * (0.5 * e1 - xd[q * 4 + 1]);
                u += e2 * (0.5 * e2 - xd[q * 4 + 2]);
                u += e3 * (0.5 * e3 - xd[q * 4 + 3]);
            }
            u += __shfl_xor(u, 1);
            u += __shfl_xor(u, 2);
            if (u < best) { best = u; bi = k; }
        }
        for (int off = 4; off < 64; off <<= 1) {
            double ob = __shfl_down(best, off);
            int oi = __shfl_down(bi, off);
            if (ob < best || (ob == best && oi < bi)) { best = ob; bi = oi; }
        }
        int newi = __shfl(bi, 0);
        int oldi = idxp[n];
        if (newi != oldi && kg == 0) {    // lanes 0..3 fix q + loss delta
            const float4* eo = (const float4*)(emb + oldi * DIM + dg * 16);
            const float4* en = (const float4*)(emb + newi * DIM + dg * 16);
            double dl = 0.0;
#pragma unroll
            for (int q = 0; q < 4; ++q) {
                float4 vo = eo[q], vn = en[q];
#pragma unroll
                for (int jc = 0; jc < 4; ++jc) {
                    double xe = xd[q * 4 + jc];
                    double nn = (double)(&vn.x)[jc] - xe;
                    double oo = (double)(&vo.x)[jc] - xe;
                    dl += nn * nn - oo * oo;
                    out[OUT_Q + xoff + (dg * 16 + q * 4 + jc) * 4096] =
                        (&vn.x)[jc];
                }
            }
            dl += __shfl_xor(dl, 1);
            dl += __shfl_xor(dl, 2);
            if (lane == 0) {
                atomicAdd(lossadj, dl);
                atomicSub(&counts[oldi], 1);
                atomicAdd(&counts[newi], 1);
                float* enc = out + OUT_ENC;
                enc[(size_t)n * 1024 + oldi] = 0.0f;
                enc[(size_t)n * 1024 + newi] = 1.0f;
            }
        }
    }

    // ---- done-counter election: last of 256 blocks runs finalize ----
    __shared__ int isLast;
    __threadfence();
    if (tid == 0) isLast = (atomicAdd(&flagcount[1], 1) == 255);
    __syncthreads();
    if (!isLast) return;
    __threadfence();   // acquire: see all other blocks' counts/lossadj

    __shared__ double redv[4], redl2[4];
    double v = 0.0, l = 0.0;
#pragma unroll
    for (int i = 0; i < 4; ++i) {
        double p = (double)counts[tid * 4 + i] / 32768.0;
        v += p * log(p + 1e-10);
        l += lossp[tid * 4 + i];
    }
    for (int off = 32; off > 0; off >>= 1) {
        v += __shfl_down(v, off);
        l += __shfl_down(l, off);
    }
    if ((tid & 63) == 0) { redv[tid >> 6] = v; redl2[tid >> 6] = l; }
    __syncthreads();
    if (tid == 0) {
        double sv = redv[0] + redv[1] + redv[2] + redv[3];
        double sl = redl2[0] + redl2[1] + redl2[2] + redl2[3];
        out[OUT_PERP] = (float)exp(-sv);
        out[0] = (float)((sl + lossadj[0]) * (1.25 / 2097152.0));
    }
}

// ---------------------------------------------------------------------------
extern "C" void kernel_launch(void* const* d_in, const int* in_sizes, int n_in,
                              void* d_out, int out_size, void* d_ws,
                              size_t ws_size, hipStream_t stream) {
    (void)in_sizes; (void)n_in; (void)out_size; (void)ws_size;
    const float* x = (const float*)d_in[0];
    const float* emb = (const float*)d_in[1];
    float* out = (float*)d_out;
    char* p = (char*)d_ws;

    // all scratch in d_ws (~541 KB)
    unsigned short* epack = (unsigned short*)p; p += 262144;  // 256 KB
    int* idxp = (int*)p;        p += 131072;
    int* flaglist = (int*)p;    p += 131072;
    float* sqnB21 = (float*)p;  p += 4096;
    int* counts = (int*)p;      p += 4096;
    double* lossp = (double*)p; p += 8192;    // 1024 per-block partials
    int* flagcount = (int*)p;   p += 8;       // [0]=flags, [1]=done-counter
    double* lossadj = (double*)p;

    vq_prep_kernel<<<64, 256, 0, stream>>>(emb, sqnB21, epack, counts,
                                           flagcount, lossadj);
    vq_mega_kernel<<<1024, 256, 0, stream>>>(x, emb, epack, sqnB21, out, idxp,
                                             flaglist, flagcount, counts,
                                             lossp);
    vq_patchfin_kernel<<<256, 256, 0, stream>>>(x, emb, flaglist, flagcount,
                                                idxp, out, counts, lossadj,
                                                lossp);
}

// Round 18
// 75.838 us; speedup vs baseline: 1.2730x; 1.2730x over previous
//
#include <hip/hip_runtime.h>
#include <math.h>

#define N_ROWS 32768
#define KCODES 1024
#define DIM 64
#define OUT_Q 1
#define OUT_PERP 2097153
#define OUT_ENC 2097154
#define GAP_QUANTA 64u   // 64 * 2^-21 ~ 3.05e-5 >> bf16-split dot err (~1e-6)

using short8 = __attribute__((ext_vector_type(8))) short;   // 8 bf16 (4 VGPR)
using f32x4  = __attribute__((ext_vector_type(4))) float;
typedef float f32x2 __attribute__((ext_vector_type(2)));

__device__ __forceinline__ unsigned umin_(unsigned a, unsigned b){return a<b?a:b;}
__device__ __forceinline__ unsigned umax_(unsigned a, unsigned b){return a>b?a:b;}
// RTNE float->bf16
__device__ __forceinline__ unsigned short f2bf(float f){
    unsigned u = __float_as_uint(f);
    unsigned r = (u + 0x7FFFu + ((u >> 16) & 1u)) >> 16;
    return (unsigned short)r;
}
__device__ __forceinline__ float bf2f(unsigned short h){
    return __uint_as_float(((unsigned)h) << 16);
}

// ---------------------------------------------------------------------------
// P: prep (64 blocks; one thread per (code, float4-chunk)).
// sqnB21[k] = (0.25 + 0.5||e_k||^2)*2^21 (fp64, 16-lane shfl reduce);
// codebook bf16-split packed in MFMA-fragment order (epack, in d_ws).
// Zeroes counts/flagcount/lossadj.
// ---------------------------------------------------------------------------
__global__ __launch_bounds__(256) void vq_prep_kernel(
    const float* __restrict__ emb, float* __restrict__ sqnB21,
    unsigned short* __restrict__ epack, int* __restrict__ counts,
    int* __restrict__ flagcount, double* __restrict__ lossadj) {
    int t = blockIdx.x * 256 + threadIdx.x;  // 16384 threads
    int k = t >> 4, q = t & 15;
    if (t < KCODES) counts[t] = 0;
    if (t == 0) { flagcount[0] = 0; lossadj[0] = 0.0; }
    int tile = k >> 4, col = k & 15;
    float4 v = ((const float4*)emb)[t];      // = emb[k*64 + q*4 ..]
    unsigned short h0=f2bf(v.x), h1=f2bf(v.y), h2=f2bf(v.z), h3=f2bf(v.w);
    unsigned short l0=f2bf(v.x-bf2f(h0)), l1=f2bf(v.y-bf2f(h1)),
                   l2=f2bf(v.z-bf2f(h2)), l3=f2bf(v.w-bf2f(h3));
    unsigned* up = (unsigned*)epack;
    unsigned idx = tile * 1024u + (q >> 1) * 64u + col * 4u + (q & 1) * 2u;
    up[idx]       = (unsigned)h0 | ((unsigned)h1 << 16);
    up[idx + 1]   = (unsigned)h2 | ((unsigned)h3 << 16);
    up[idx + 512] = (unsigned)l0 | ((unsigned)l1 << 16);
    up[idx + 513] = (unsigned)l2 | ((unsigned)l3 << 16);
    double s = (double)v.x*v.x + (double)v.y*v.y +
               (double)v.z*v.z + (double)v.w*v.w;
    s += __shfl_xor(s, 1);
    s += __shfl_xor(s, 2);
    s += __shfl_xor(s, 4);
    s += __shfl_xor(s, 8);
    if (q == 0) sqnB21[k] = (float)((0.25 + 0.5 * s) * 2097152.0);
}

// ---------------------------------------------------------------------------
// M: MEGA kernel (r16 structure) — 1024 blocks x 32 rows, in-block K-split
// (4 blocks/CU). Wave w = (rowgroup w&1, khalf w>>1): scans 512 codes for
// its 16 rows. Interleaved enc zero-stream (1 f32x4/lane/tile-iter).
// SINGLE CHANGE vs r16: q+loss computed from the A-fragments (x_rec = h+l,
// rel err ~8e-6 << 2% threshold) with ALL 4 waves participating — wave
// (rg,kh) covers its 16 rows x d in [kh*32, kh*32+32). No x re-read.
// ---------------------------------------------------------------------------
__global__ __launch_bounds__(256, 4) void vq_mega_kernel(
    const float* __restrict__ x, const float* __restrict__ emb,
    const unsigned short* __restrict__ epack,
    const float* __restrict__ sqnB21, float* __restrict__ out,
    int* __restrict__ idxp, int* __restrict__ flaglist,
    int* __restrict__ flagcount, int* __restrict__ counts,
    double* __restrict__ lossp) {
    __shared__ short8 elds[8 * 256];             // 32 KB: 4+4 tiles
    __shared__ unsigned sbb[4][16], sss[4][16];
    __shared__ int sidx[32];
    __shared__ double redl[4];
    int tid = threadIdx.x;
    int bi = blockIdx.x;          // 1024 blocks x 32 rows
    int lane = tid & 63;
    int w = tid >> 6;
    int rg = w & 1;               // row-group (16 rows)
    int kh = w >> 1;              // K-half (512 codes)
    int col = lane & 15;
    int g = lane >> 4;
    int n = bi * 32 + rg * 16 + col;
    int xbase = (n >> 12) * 262144 + (n & 4095);

    // wave's enc zero region: 8 rows = 8192 floats (region base ≡8 mod 16)
    float* enc = out + OUT_ENC;
    float* zreg = enc + (size_t)(bi * 32 + w * 8) * 1024;
    f32x4* zvec = (f32x4*)(zreg + 2);
    const f32x4 zz4 = {0.f, 0.f, 0.f, 0.f};
    const f32x2 zz2 = {0.f, 0.f};

    short8 ah0, al0, ah1, al1;
#pragma unroll
    for (int j = 0; j < 8; ++j) {
        float v0 = x[xbase + (g * 8 + j) * 4096];
        unsigned short h0 = f2bf(v0);
        ah0[j] = (short)h0; al0[j] = (short)f2bf(v0 - bf2f(h0));
        float v1 = x[xbase + (32 + g * 8 + j) * 4096];
        unsigned short h1 = f2bf(v1);
        ah1[j] = (short)h1; al1[j] = (short)f2bf(v1 - bf2f(h1));
    }

    unsigned best[4] = {~0u, ~0u, ~0u, ~0u}, sec[4] = {~0u, ~0u, ~0u, ~0u};
    for (int ph = 0; ph < 8; ++ph) {
        // stage 8 tiles: slots 0..3 = khalf0 tiles ph*4+i, 4..7 = khalf1
        f32x4* dst = (f32x4*)elds;
#pragma unroll
        for (int i = 0; i < 8; ++i) {
            int tile_g = (i < 4) ? (ph * 4 + i) : (32 + ph * 4 + (i - 4));
            dst[i * 256 + tid] =
                ((const f32x4*)epack)[(size_t)tile_g * 256 + tid];
        }
        __syncthreads();
#pragma unroll
        for (int tt = 0; tt < 4; ++tt) {
            // interleaved enc zero-store (drains under MFMA)
            int zslot = (ph * 4 + tt) * 64 + lane;
            if (zslot < 2047) zvec[zslot] = zz4;
            else {
                *(f32x2*)zreg = zz2;
                *(f32x2*)(zreg + 8190) = zz2;
            }

            int code = (kh * 32 + ph * 4 + tt) * 16 + col;
            const short8* bp = elds + (kh * 4 + tt) * 256;
            short8 bh0 = bp[lane];        // h, d 0..31
            short8 bh1 = bp[64 + lane];   // h, d 32..63
            short8 bl0 = bp[128 + lane];  // l, d 0..31
            short8 bl1 = bp[192 + lane];  // l, d 32..63
            float sqv = sqnB21[code];
            f32x4 a0 = {0.f, 0.f, 0.f, 0.f}, a1 = {0.f, 0.f, 0.f, 0.f};
            a0 = __builtin_amdgcn_mfma_f32_16x16x32_bf16(ah0, bh0, a0, 0, 0, 0);
            a0 = __builtin_amdgcn_mfma_f32_16x16x32_bf16(ah1, bh1, a0, 0, 0, 0);
            a1 = __builtin_amdgcn_mfma_f32_16x16x32_bf16(ah0, bl0, a1, 0, 0, 0);
            a1 = __builtin_amdgcn_mfma_f32_16x16x32_bf16(al0, bh0, a1, 0, 0, 0);
            a1 = __builtin_amdgcn_mfma_f32_16x16x32_bf16(ah1, bl1, a1, 0, 0, 0);
            a1 = __builtin_amdgcn_mfma_f32_16x16x32_bf16(al1, bh1, a1, 0, 0, 0);
#pragma unroll
            for (int r = 0; r < 4; ++r) {
                float s = a0[r] + a1[r];
                unsigned u = (unsigned)fmaf(s, -2097152.0f, sqv);
                unsigned pk = (u << 10) | (unsigned)code;
                unsigned t = umax_(pk, best[r]);
                sec[r] = umin_(sec[r], t);
                best[r] = umin_(best[r], pk);
            }
        }
        __syncthreads();   // protect LDS; drains this phase's stores
    }
    // xor-reduce over the 16 code-columns within each 16-lane group
#pragma unroll
    for (int st = 1; st < 16; st <<= 1) {
#pragma unroll
        for (int r = 0; r < 4; ++r) {
            unsigned ob = __shfl_xor(best[r], st);
            unsigned os = __shfl_xor(sec[r], st);
            sec[r] = umin_(umin_(sec[r], os), umax_(best[r], ob));
            best[r] = umin_(best[r], ob);
        }
    }
    if (col == 0) {
#pragma unroll
        for (int r = 0; r < 4; ++r) {
            sbb[w][g * 4 + r] = best[r];
            sss[w][g * 4 + r] = sec[r];
        }
    }
    __syncthreads();
    // K-merge across wave pairs (rg, rg+2); idx/counts/flag for 32 rows
    if (tid < 32) {
        int rg2 = tid >> 4, r16 = tid & 15;
        unsigned b0 = sbb[rg2][r16], s0 = sss[rg2][r16];
        unsigned b1 = sbb[rg2 + 2][r16], s1 = sss[rg2 + 2][r16];
        unsigned s = umin_(umin_(s0, s1), umax_(b0, b1));
        unsigned b = umin_(b0, b1);
        int n2 = bi * 32 + tid;
        int ix = (int)(b & 1023u);
        sidx[tid] = ix;
        idxp[n2] = ix;
        atomicAdd(&counts[ix], 1);
        if (((s >> 10) - (b >> 10)) < GAP_QUANTA) {
            int pos = atomicAdd(flagcount, 1);
            flaglist[pos] = n2;
        }
    }
    __syncthreads();   // vmcnt(0) drain: zeros complete before the ones

    // ---- ones scatter ----
    if (tid < 32) {
        int n2 = bi * 32 + tid;
        enc[(size_t)n2 * 1024 + sidx[tid]] = 1.0f;
    }

    // ---- q + loss FROM FRAGMENTS: all 4 waves; kh selects d-half ----
    {
        int iv = sidx[rg * 16 + col];
        const float4* e4 = (const float4*)(emb + iv * DIM + kh * 32 + g * 8);
        float* qp = out + OUT_Q + xbase + kh * 32 * 4096;
        short8 hf = (kh == 0) ? ah0 : ah1;   // wave-uniform select
        short8 lf = (kh == 0) ? al0 : al1;
        float lsum = 0.f;
#pragma unroll
        for (int q = 0; q < 2; ++q) {
            float4 ev = e4[q];
#pragma unroll
            for (int jc = 0; jc < 4; ++jc) {
                int j = q * 4 + jc;
                float xr = bf2f((unsigned short)hf[j]) +
                           bf2f((unsigned short)lf[j]);
                float e = (&ev.x)[jc];
                float df = e - xr;
                lsum += df * df;
                qp[(g * 8 + j) * 4096] = e;
            }
        }
        double ls = (double)lsum;
        for (int off = 32; off > 0; off >>= 1) ls += __shfl_down(ls, off);
        if (lane == 0) redl[w] = ls;
    }
    __syncthreads();
    if (tid == 0) lossp[bi] = redl[0] + redl[1] + redl[2] + redl[3];
}

// ---------------------------------------------------------------------------
// B: patch — exact fp64 re-scan of flagged rows (one wave per row); if the
// winner changes, fix enc (old->0, new->1), rewrite q row, adjust counts and
// add the fp64 loss delta to lossadj.
// ---------------------------------------------------------------------------
__global__ __launch_bounds__(256) void vq_patch_kernel(
    const float* __restrict__ x, const float* __restrict__ emb,
    const int* __restrict__ flaglist, const int* __restrict__ flagcount,
    const int* __restrict__ idxp, float* __restrict__ out,
    int* __restrict__ counts, double* __restrict__ lossadj) {
    int lane = threadIdx.x & 63;
    int gw = (blockIdx.x * blockDim.x + threadIdx.x) >> 6;  // 0..1023
    int nf = flagcount[0];
    int dg = lane & 3, kg = lane >> 2;
    for (int i = gw; i < nf; i += 1024) {
        int n = flaglist[i];
        int xoff = (n >> 12) * 262144 + (n & 4095);
        const float* xp = x + xoff + dg * 16 * 4096;
        double xd[16];
#pragma unroll
        for (int j = 0; j < 16; ++j) xd[j] = (double)xp[j * 4096];
        double best = 1e300;
        int bi = 0;
        for (int j = 0; j < 64; ++j) {
            int k = kg * 64 + j;
            const float4* e4 = (const float4*)(emb + k * DIM + dg * 16);
            double u = 0.0;
#pragma unroll
            for (int q = 0; q < 4; ++q) {
                float4 ev = e4[q];
                double e0 = ev.x, e1 = ev.y, e2 = ev.z, e3 = ev.w;
                u += e0 * (0.5 * e0 - xd[q * 4 + 0]);
                u += e1 * (0.5 * e1 - xd[q * 4 + 1]);
                u += e2 * (0.5 * e2 - xd[q * 4 + 2]);
                u += e3 * (0.5 * e3 - xd[q * 4 + 3]);
            }
            u += __shfl_xor(u, 1);
            u += __shfl_xor(u, 2);
            if (u < best) { best = u; bi = k; }
        }
        for (int off = 4; off < 64; off <<= 1) {
            double ob = __shfl_down(best, off);
            int oi = __shfl_down(bi, off);
            if (ob < best || (ob == best && oi < bi)) { best = ob; bi = oi; }
        }
        int newi = __shfl(bi, 0);
        int oldi = idxp[n];
        if (newi != oldi && kg == 0) {    // lanes 0..3 fix q + loss delta
            const float4* eo = (const float4*)(emb + oldi * DIM + dg * 16);
            const float4* en = (const float4*)(emb + newi * DIM + dg * 16);
            double dl = 0.0;
#pragma unroll
            for (int q = 0; q < 4; ++q) {
                float4 vo = eo[q], vn = en[q];
#pragma unroll
                for (int jc = 0; jc < 4; ++jc) {
                    double xe = xd[q * 4 + jc];
                    double nn = (double)(&vn.x)[jc] - xe;
                    double oo = (double)(&vo.x)[jc] - xe;
                    dl += nn * nn - oo * oo;
                    out[OUT_Q + xoff + (dg * 16 + q * 4 + jc) * 4096] =
                        (&vn.x)[jc];
                }
            }
            dl += __shfl_xor(dl, 1);
            dl += __shfl_xor(dl, 2);
            if (lane == 0) {
                atomicAdd(lossadj, dl);
                atomicSub(&counts[oldi], 1);
                atomicAdd(&counts[newi], 1);
                float* enc = out + OUT_ENC;
                enc[(size_t)n * 1024 + oldi] = 0.0f;
                enc[(size_t)n * 1024 + newi] = 1.0f;
            }
        }
    }
}

// ---------------------------------------------------------------------------
// D: perplexity + loss scalars (counts entropy + lossp partials + lossadj).
// ---------------------------------------------------------------------------
__global__ void vq_finalize_kernel(const int* __restrict__ counts,
                                   const double* __restrict__ lossp,
                                   const double* __restrict__ lossadj,
                                   float* __restrict__ out) {
    __shared__ double redv[16], redl[16];
    int t = threadIdx.x;  // 1024
    double p = (double)counts[t] / 32768.0;
    double v = p * log(p + 1e-10);
    double l = lossp[t];
    for (int off = 32; off > 0; off >>= 1) {
        v += __shfl_down(v, off);
        l += __shfl_down(l, off);
    }
    if ((t & 63) == 0) { redv[t >> 6] = v; redl[t >> 6] = l; }
    __syncthreads();
    if (t == 0) {
        double sv = 0.0, sl = 0.0;
#pragma unroll
        for (int i = 0; i < 16; ++i) { sv += redv[i]; sl += redl[i]; }
        out[OUT_PERP] = (float)exp(-sv);
        out[0] = (float)((sl + lossadj[0]) * (1.25 / 2097152.0));
    }
}

// ---------------------------------------------------------------------------
extern "C" void kernel_launch(void* const* d_in, const int* in_sizes, int n_in,
                              void* d_out, int out_size, void* d_ws,
                              size_t ws_size, hipStream_t stream) {
    (void)in_sizes; (void)n_in; (void)out_size; (void)ws_size;
    const float* x = (const float*)d_in[0];
    const float* emb = (const float*)d_in[1];
    float* out = (float*)d_out;
    char* p = (char*)d_ws;

    // all scratch in d_ws (~541 KB)
    unsigned short* epack = (unsigned short*)p; p += 262144;  // 256 KB
    int* idxp = (int*)p;        p += 131072;
    int* flaglist = (int*)p;    p += 131072;
    float* sqnB21 = (float*)p;  p += 4096;
    int* counts = (int*)p;      p += 4096;
    double* lossp = (double*)p; p += 8192;    // 1024 per-block partials
    int* flagcount = (int*)p;   p += 8;       // 4 + pad
    double* lossadj = (double*)p;

    vq_prep_kernel<<<64, 256, 0, stream>>>(emb, sqnB21, epack, counts,
                                           flagcount, lossadj);
    vq_mega_kernel<<<1024, 256, 0, stream>>>(x, emb, epack, sqnB21, out, idxp,
                                             flaglist, flagcount, counts,
                                             lossp);
    vq_patch_kernel<<<256, 256, 0, stream>>>(x, emb, flaglist, flagcount,
                                             idxp, out, counts, lossadj);
    vq_finalize_kernel<<<1, 1024, 0, stream>>>(counts, lossp, lossadj, out);
}